// Round 2
// baseline (517.113 us; speedup 1.0000x reference)
//
#include <hip/hip_runtime.h>

// Dtype-agnostic version. Device-side probes determine at runtime:
//   flags[0] = 1 if float tensors are float32, 0 if bf16-packed
//   flags[1] = 1 if edge_index is int64, 0 if int32
// Compute path: bf16 MFMA 16x16x32 (f32 accumulate) for both node MLPs,
// f32 node tables (Atab/Btab) in d_ws, then per-edge scoring kernel.
// d_ws layout: Atab f32[2*50000*16] | Btab f32[2*50000*16] | flags int[2]

typedef unsigned short u16;
typedef unsigned int   u32;
typedef __attribute__((ext_vector_type(8))) short short8;
typedef __attribute__((ext_vector_type(4))) float f32x4;

#define N_NODES 50000
#define BATCH   2
#define T_STEPS 8
#define C_DIM   64
#define HID     128
#define R_DIM   16
#define L_DIM   12
#define E_EDGES 1600000
#define TILES   6250        // (BATCH*N_NODES)/16, exact
#define HSTRIDE 136         // padded LDS hidden row stride (bf16 elems), 272B (16B-aligned)
#define TAB_ELEMS ((size_t)BATCH * N_NODES * R_DIM)

__device__ __forceinline__ float bf2f(u16 u) {
  unsigned v = ((unsigned)u) << 16;
  return __builtin_bit_cast(float, v);
}
__device__ __forceinline__ u16 f2bf(float f) {
  unsigned x = __builtin_bit_cast(unsigned, f);
  x += 0x7fffu + ((x >> 16) & 1u);
  return (u16)(x >> 16);
}
// dtype-agnostic scalar loads
__device__ __forceinline__ u16 ld_bf(const void* p, int idx, bool f32) {
  return f32 ? f2bf(((const float*)p)[idx]) : ((const u16*)p)[idx];
}
__device__ __forceinline__ float ld_f(const void* p, int idx, bool f32) {
  return f32 ? ((const float*)p)[idx] : bf2f(((const u16*)p)[idx]);
}

// ---------------------------------------------------------------------------
// Probe kernel: decide f32-vs-bf16 (floats) and i64-vs-i32 (edge_index).
// ---------------------------------------------------------------------------
__global__ __launch_bounds__(256) void detect_kernel(
    const u16* __restrict__ w1u, const u32* __restrict__ eraw, int* flags)
{
  __shared__ int cnt, zcnt;
  const int t = threadIdx.x;
  if (t == 0) { cnt = 0; zcnt = 0; }
  __syncthreads();
  int c = 0;
#pragma unroll
  for (int i = 0; i < 8; ++i) {
    u16 u = w1u[t * 8 + i];          // first 2048 u16s of W1s (8192 elems either way)
    int e = (u >> 7) & 0xFF;         // bf16 exponent field position
    if (e >= 100 && e <= 127) c++;
  }
  atomicAdd(&cnt, c);
  if (t < 64 && eraw[2 * t + 1] == 0) atomicAdd(&zcnt, 1);
  __syncthreads();
  if (t == 0) {
    flags[0] = (cnt < 1638) ? 1 : 0;  // <80% structured exponents => float32
    flags[1] = (zcnt == 64) ? 1 : 0;  // all odd words zero => int64
  }
}

// ---------------------------------------------------------------------------
// Kernel 1: per-node two-layer MLPs (s and d) via MFMA 16x16x32 bf16.
// One wave = 16 nodes. Weight B-frags in registers; layer1->relu->per-wave LDS
// (bf16) -> layer2 A-frags. Same-wave LDS exchange, no barriers needed.
// ---------------------------------------------------------------------------
__global__ __launch_bounds__(256, 1) void mlp_kernel(
    const void* __restrict__ X,
    const void* __restrict__ W1s, const void* __restrict__ b1s,
    const void* __restrict__ W2s, const void* __restrict__ b2s,
    const void* __restrict__ W1d, const void* __restrict__ b1d,
    const void* __restrict__ W2d, const void* __restrict__ b2d,
    float* __restrict__ Atab, float* __restrict__ Btab,
    const int* __restrict__ flags)
{
  __shared__ u16 hid[4][2][16 * HSTRIDE];   // [wave][mlp][16 nodes x 136] = 34816 B

  const bool isf32 = flags[0] != 0;
  const int tid  = threadIdx.x;
  const int wave = tid >> 6;
  const int lane = tid & 63;
  const int nl   = lane & 15;   // MFMA 16-dim index
  const int quad = lane >> 4;

  const void* W1p[2] = {W1s, W1d};
  const void* W2p[2] = {W2s, W2d};
  const void* b1p[2] = {b1s, b1d};
  const void* b2p[2] = {b2s, b2d};

  // ---- one-time per-wave weight fragment loads (L2-resident, tiny) ----
  // Layer1 B-frag: B[k = kt*32 + quad*8 + j][n = ct*16 + nl], W1 is (64,128) row-major
  short8 w1f[2][8][2];
#pragma unroll
  for (int m = 0; m < 2; ++m)
#pragma unroll
    for (int ct = 0; ct < 8; ++ct)
#pragma unroll
      for (int kt = 0; kt < 2; ++kt) {
        short8 f;
#pragma unroll
        for (int j = 0; j < 8; ++j) {
          int k = kt * 32 + quad * 8 + j;
          f[j] = (short)ld_bf(W1p[m], k * HID + ct * 16 + nl, isf32);
        }
        w1f[m][ct][kt] = f;
      }
  // Layer2 B-frag: B[k = kt*32 + quad*8 + j][r = nl], W2 is (128,16) row-major
  short8 w2f[2][4];
#pragma unroll
  for (int m = 0; m < 2; ++m)
#pragma unroll
    for (int kt = 0; kt < 4; ++kt) {
      short8 f;
#pragma unroll
      for (int j = 0; j < 8; ++j) {
        int k = kt * 32 + quad * 8 + j;
        f[j] = (short)ld_bf(W2p[m], k * R_DIM + nl, isf32);
      }
      w2f[m][kt] = f;
    }
  float b1v[2][8], b2v[2];
#pragma unroll
  for (int m = 0; m < 2; ++m) {
#pragma unroll
    for (int ct = 0; ct < 8; ++ct) b1v[m][ct] = ld_f(b1p[m], ct * 16 + nl, isf32);
    b2v[m] = ld_f(b2p[m], nl, isf32);
  }

  for (int tile = blockIdx.x * 4 + wave; tile < TILES; tile += gridDim.x * 4) {
    const int g0 = tile * 16;
    const int g = g0 + nl;
    const int bb = (g >= N_NODES) ? 1 : 0;
    const int n = g - bb * N_NODES;
    const size_t rowoff = (size_t)((bb * T_STEPS + (T_STEPS - 1)) * N_NODES + n) * C_DIM;

    // Layer1 A-frag: A[m = nl][k = kt*32 + quad*8 + j] = H[node g][c = k]
    short8 af0, af1;
    if (isf32) {
      const float* xf = (const float*)X + rowoff;
#pragma unroll
      for (int j = 0; j < 8; ++j) {
        af0[j] = (short)f2bf(xf[quad * 8 + j]);
        af1[j] = (short)f2bf(xf[32 + quad * 8 + j]);
      }
    } else {
      const u16* xb = (const u16*)X + rowoff;
      af0 = *(const short8*)(xb + quad * 8);
      af1 = *(const short8*)(xb + 32 + quad * 8);
    }

#pragma unroll
    for (int m = 0; m < 2; ++m) {
      u16* hm = &hid[wave][m][0];
#pragma unroll
      for (int ct = 0; ct < 8; ++ct) {
        f32x4 acc = {b1v[m][ct], b1v[m][ct], b1v[m][ct], b1v[m][ct]};
        acc = __builtin_amdgcn_mfma_f32_16x16x32_bf16(af0, w1f[m][ct][0], acc, 0, 0, 0);
        acc = __builtin_amdgcn_mfma_f32_16x16x32_bf16(af1, w1f[m][ct][1], acc, 0, 0, 0);
        // D[row = quad*4+i][col = nl] -> hidden[node row][unit ct*16+nl], relu, bf16
#pragma unroll
        for (int i = 0; i < 4; ++i) {
          float h = acc[i] > 0.f ? acc[i] : 0.f;
          hm[(quad * 4 + i) * HSTRIDE + ct * 16 + nl] = f2bf(h);
        }
      }
    }

    // Layer2: A2[m = nl][k = kt*32 + quad*8 + j] from per-wave LDS
#pragma unroll
    for (int m = 0; m < 2; ++m) {
      const u16* hm = &hid[wave][m][0];
      f32x4 acc = {b2v[m], b2v[m], b2v[m], b2v[m]};
#pragma unroll
      for (int kt = 0; kt < 4; ++kt) {
        short8 a2 = *(const short8*)(hm + nl * HSTRIDE + kt * 32 + quad * 8);
        acc = __builtin_amdgcn_mfma_f32_16x16x32_bf16(a2, w2f[m][kt], acc, 0, 0, 0);
      }
      float* outp = (m == 0) ? Atab : Btab;
#pragma unroll
      for (int i = 0; i < 4; ++i)
        outp[(size_t)(g0 + quad * 4 + i) * R_DIM + nl] = acc[i];
    }
  }
}

// ---------------------------------------------------------------------------
// Kernel 2: edge scoring. One thread per edge; both batches, all 12 l's.
// logits[b,l,e] = sum_r a[b,I[e],r] * gamma[l,r] * b[b,J[e],r]
// ---------------------------------------------------------------------------
__global__ __launch_bounds__(256) void edge_kernel(
    const void* __restrict__ eidx,
    const float* __restrict__ Atab, const float* __restrict__ Btab,
    const void* __restrict__ gamma, void* __restrict__ out,
    const int* __restrict__ flags)
{
  __shared__ float gf[L_DIM * R_DIM];
  const bool isf32 = flags[0] != 0;
  const bool isi64 = flags[1] != 0;
  const int tid = threadIdx.x;
  if (tid < L_DIM * R_DIM) gf[tid] = ld_f(gamma, tid, isf32);
  __syncthreads();

  const int e = blockIdx.x * 256 + tid;   // grid sized exactly: 6250*256 = E
  int inode, jnode;
  if (isi64) {
    const long long* e64 = (const long long*)eidx;
    inode = (int)e64[e];
    jnode = (int)e64[E_EDGES + e];
  } else {
    const int* e32 = (const int*)eidx;
    inode = e32[e];
    jnode = e32[E_EDGES + e];
  }

  float4 p[2][4];
#pragma unroll
  for (int b = 0; b < 2; ++b) {
    const float4* ap = (const float4*)(Atab + (size_t)(b * N_NODES + inode) * R_DIM);
    const float4* bp = (const float4*)(Btab + (size_t)(b * N_NODES + jnode) * R_DIM);
#pragma unroll
    for (int q = 0; q < 4; ++q) {
      float4 av = ap[q], bv = bp[q];
      p[b][q] = make_float4(av.x * bv.x, av.y * bv.y, av.z * bv.z, av.w * bv.w);
    }
  }

  const float4* gv = (const float4*)gf;
#pragma unroll
  for (int l = 0; l < L_DIM; ++l) {
    float s0 = 0.f, s1 = 0.f;
#pragma unroll
    for (int q = 0; q < 4; ++q) {
      float4 g4 = gv[l * 4 + q];
      s0 += g4.x * p[0][q].x + g4.y * p[0][q].y + g4.z * p[0][q].z + g4.w * p[0][q].w;
      s1 += g4.x * p[1][q].x + g4.y * p[1][q].y + g4.z * p[1][q].z + g4.w * p[1][q].w;
    }
    size_t i0 = (size_t)l * E_EDGES + e;
    size_t i1 = (size_t)(L_DIM + l) * E_EDGES + e;
    if (isf32) {
      float* of = (float*)out;
      of[i0] = s0; of[i1] = s1;
    } else {
      u16* ob = (u16*)out;
      ob[i0] = f2bf(s0); ob[i1] = f2bf(s1);
    }
  }
}

extern "C" void kernel_launch(void* const* d_in, const int* in_sizes, int n_in,
                              void* d_out, int out_size, void* d_ws, size_t ws_size,
                              hipStream_t stream) {
  const void* X     = d_in[0];
  const void* eidx  = d_in[1];
  const void* W1s   = d_in[2];
  const void* b1s   = d_in[3];
  const void* W2s   = d_in[4];
  const void* b2s   = d_in[5];
  const void* W1d   = d_in[6];
  const void* b1d   = d_in[7];
  const void* W2d   = d_in[8];
  const void* b2d   = d_in[9];
  const void* gamma = d_in[10];

  float* Atab = (float*)d_ws;
  float* Btab = Atab + TAB_ELEMS;
  int* flags  = (int*)(Btab + TAB_ELEMS);

  hipLaunchKernelGGL(detect_kernel, dim3(1), dim3(256), 0, stream,
                     (const u16*)W1s, (const u32*)eidx, flags);
  hipLaunchKernelGGL(mlp_kernel, dim3(512), dim3(256), 0, stream,
                     X, W1s, b1s, W2s, b2s, W1d, b1d, W2d, b2d, Atab, Btab, flags);
  hipLaunchKernelGGL(edge_kernel, dim3(E_EDGES / 256), dim3(256), 0, stream,
                     eidx, Atab, Btab, gamma, d_out, flags);
}

// Round 3
// 386.542 us; speedup vs baseline: 1.3378x; 1.3378x over previous
//
#include <hip/hip_runtime.h>

// Dtype-agnostic (device probe): flags[0]=1 if floats are f32 (evidence says bf16),
// flags[1]=1 if edge_index is int64.
// mlp_kernel: weights staged to LDS (transposed, padded) once per block; all MFMA
// fragments come from conflict-free ds_read_b128. Node tables written as bf16
// interleaved [node][batch][r] (one cache line per gathered node).
// d_ws layout: Atb u16[50000*32] | Btb u16[50000*32] | flags int[2]

typedef unsigned short u16;
typedef unsigned int   u32;
typedef __attribute__((ext_vector_type(8))) short short8;
typedef __attribute__((ext_vector_type(4))) float f32x4;

#define N_NODES 50000
#define T_STEPS 8
#define C_DIM   64
#define HID     128
#define R_DIM   16
#define L_DIM   12
#define E_EDGES 1600000
#define TILES   6250        // (2*N_NODES)/16, exact; 3125 tiles per batch (no straddle)
#define HSTRIDE 136         // hid row stride (bf16 elems), 272B: b128-aligned, conflict-free
#define W1S     72          // w1t row stride (64+8)
#define W2S     136         // w2t row stride (128+8)
#define TAB_U16 ((size_t)N_NODES * 32)

__device__ __forceinline__ float bf2f(u16 u) {
  unsigned v = ((unsigned)u) << 16;
  return __builtin_bit_cast(float, v);
}
__device__ __forceinline__ u16 f2bf(float f) {
  unsigned x = __builtin_bit_cast(unsigned, f);
  x += 0x7fffu + ((x >> 16) & 1u);
  return (u16)(x >> 16);
}
__device__ __forceinline__ u16 ld_bf(const void* p, int idx, bool f32) {
  return f32 ? f2bf(((const float*)p)[idx]) : ((const u16*)p)[idx];
}
__device__ __forceinline__ float ld_f(const void* p, int idx, bool f32) {
  return f32 ? ((const float*)p)[idx] : bf2f(((const u16*)p)[idx]);
}

// ---------------------------------------------------------------------------
__global__ __launch_bounds__(256) void detect_kernel(
    const u16* __restrict__ w1u, const u32* __restrict__ eraw, int* flags)
{
  __shared__ int cnt, zcnt;
  const int t = threadIdx.x;
  if (t == 0) { cnt = 0; zcnt = 0; }
  __syncthreads();
  int c = 0;
#pragma unroll
  for (int i = 0; i < 8; ++i) {
    u16 u = w1u[t * 8 + i];
    int e = (u >> 7) & 0xFF;
    if (e >= 100 && e <= 127) c++;
  }
  atomicAdd(&cnt, c);
  if (t < 64 && eraw[2 * t + 1] == 0) atomicAdd(&zcnt, 1);
  __syncthreads();
  if (t == 0) {
    flags[0] = (cnt < 1638) ? 1 : 0;
    flags[1] = (zcnt == 64) ? 1 : 0;
  }
}

// ---------------------------------------------------------------------------
// Kernel 1: node MLPs. One wave = 16 nodes. All weights in LDS.
// LDS: w1t[2][128][72] + w2t[2][16][136] + hid[4][16][136] + biases = 64.1 KB
// ---------------------------------------------------------------------------
__global__ __launch_bounds__(256, 2) void mlp_kernel(
    const void* __restrict__ X,
    const void* __restrict__ W1s, const void* __restrict__ b1s,
    const void* __restrict__ W2s, const void* __restrict__ b2s,
    const void* __restrict__ W1d, const void* __restrict__ b1d,
    const void* __restrict__ W2d, const void* __restrict__ b2d,
    u16* __restrict__ Atb, u16* __restrict__ Btb,
    const int* __restrict__ flags)
{
  __shared__ u16 w1t[2 * HID * W1S];       // [m][n][k] (transposed W1), 36864 B
  __shared__ u16 w2t[2 * R_DIM * W2S];     // [m][r][k] (transposed W2),  8704 B
  __shared__ u16 hidb[4 * 16 * HSTRIDE];   // [wave][row][col],          17408 B
  __shared__ float b1l[2 * HID];           //                             1024 B
  __shared__ float b2l[2 * R_DIM];         //                              128 B

  const bool isf32 = flags[0] != 0;
  const int tid  = threadIdx.x;
  const int wave = tid >> 6;
  const int lane = tid & 63;
  const int nl   = lane & 15;
  const int quad = lane >> 4;

  const void* W1p[2] = {W1s, W1d};
  const void* W2p[2] = {W2s, W2d};
  const void* b1p[2] = {b1s, b1d};
  const void* b2p[2] = {b2s, b2d};

  // ---- cooperative staging: global (coalesced reads) -> LDS (transposed) ----
#pragma unroll
  for (int m = 0; m < 2; ++m) {
    for (int f = tid; f < C_DIM * HID; f += 256) {       // W1 (64,128) -> w1t[m][n][k]
      int k = f >> 7, n = f & 127;
      w1t[m * HID * W1S + n * W1S + k] = ld_bf(W1p[m], f, isf32);
    }
    for (int f = tid; f < HID * R_DIM; f += 256) {       // W2 (128,16) -> w2t[m][r][k]
      int k = f >> 4, r = f & 15;
      w2t[m * R_DIM * W2S + r * W2S + k] = ld_bf(W2p[m], f, isf32);
    }
    if (tid < HID)   b1l[m * HID + tid]   = ld_f(b1p[m], tid, isf32);
    if (tid < R_DIM) b2l[m * R_DIM + tid] = ld_f(b2p[m], tid, isf32);
  }
  __syncthreads();

  float b1v[2][8], b2v[2];
#pragma unroll
  for (int m = 0; m < 2; ++m) {
#pragma unroll
    for (int ct = 0; ct < 8; ++ct) b1v[m][ct] = b1l[m * HID + ct * 16 + nl];
    b2v[m] = b2l[m * R_DIM + nl];
  }

  u16* hw = hidb + wave * 16 * HSTRIDE;

  for (int tile = blockIdx.x * 4 + wave; tile < TILES; tile += gridDim.x * 4) {
    const int g0 = tile * 16;
    const int g = g0 + nl;
    const int bb = (g >= N_NODES) ? 1 : 0;
    const int n = g - bb * N_NODES;
    const size_t rowoff = ((size_t)(bb * T_STEPS + T_STEPS - 1) * N_NODES + n) * C_DIM;

    // A-frag for layer1: A[m=nl][k=quad*8+j (+32)]
    short8 af0, af1;
    if (isf32) {
      const float* xf = (const float*)X + rowoff;
#pragma unroll
      for (int j = 0; j < 8; ++j) {
        af0[j] = (short)f2bf(xf[quad * 8 + j]);
        af1[j] = (short)f2bf(xf[32 + quad * 8 + j]);
      }
    } else {
      const u16* xb = (const u16*)X + rowoff;
      af0 = *(const short8*)(xb + quad * 8);
      af1 = *(const short8*)(xb + 32 + quad * 8);
    }

#pragma unroll
    for (int m = 0; m < 2; ++m) {
      const u16* w1m = w1t + m * HID * W1S;
      // layer1: hidden[16 nodes][128 units], relu, -> hid LDS (bf16)
#pragma unroll
      for (int ct = 0; ct < 8; ++ct) {
        f32x4 acc = {b1v[m][ct], b1v[m][ct], b1v[m][ct], b1v[m][ct]};
        short8 bf0 = *(const short8*)(w1m + (ct * 16 + nl) * W1S + quad * 8);
        short8 bf1 = *(const short8*)(w1m + (ct * 16 + nl) * W1S + 32 + quad * 8);
        acc = __builtin_amdgcn_mfma_f32_16x16x32_bf16(af0, bf0, acc, 0, 0, 0);
        acc = __builtin_amdgcn_mfma_f32_16x16x32_bf16(af1, bf1, acc, 0, 0, 0);
#pragma unroll
        for (int i = 0; i < 4; ++i) {
          float h = acc[i] > 0.f ? acc[i] : 0.f;
          hw[(quad * 4 + i) * HSTRIDE + ct * 16 + nl] = f2bf(h);
        }
      }
      // layer2: A2[m=nl][k] from hid; B2[k][r=nl] from w2t
      const u16* w2m = w2t + m * R_DIM * W2S;
      f32x4 acc2 = {b2v[m], b2v[m], b2v[m], b2v[m]};
#pragma unroll
      for (int kt = 0; kt < 4; ++kt) {
        short8 a2  = *(const short8*)(hw + nl * HSTRIDE + kt * 32 + quad * 8);
        short8 b2f = *(const short8*)(w2m + nl * W2S + kt * 32 + quad * 8);
        acc2 = __builtin_amdgcn_mfma_f32_16x16x32_bf16(a2, b2f, acc2, 0, 0, 0);
      }
      u16* outp = (m == 0) ? Atb : Btb;
      // D[row=quad*4+i][col=nl=r] -> tab[node][batch][r] (bf16, 64B/node row)
#pragma unroll
      for (int i = 0; i < 4; ++i) {
        int gg = g0 + quad * 4 + i;
        int bo = (gg >= N_NODES) ? 1 : 0;
        int nn = gg - bo * N_NODES;
        outp[(size_t)nn * 32 + bo * 16 + nl] = f2bf(acc2[i]);
      }
    }
  }
}

// ---------------------------------------------------------------------------
// Kernel 2: edge scoring. One thread per edge; gathers one 64B line per node.
// ---------------------------------------------------------------------------
__global__ __launch_bounds__(256, 4) void edge_kernel(
    const void* __restrict__ eidx,
    const u16* __restrict__ Atb, const u16* __restrict__ Btb,
    const void* __restrict__ gamma, void* __restrict__ out,
    const int* __restrict__ flags)
{
  __shared__ float gf[L_DIM * R_DIM];
  const bool isf32 = flags[0] != 0;
  const bool isi64 = flags[1] != 0;
  const int tid = threadIdx.x;
  if (tid < L_DIM * R_DIM) gf[tid] = ld_f(gamma, tid, isf32);
  __syncthreads();

  const int e = blockIdx.x * 256 + tid;   // grid exactly E/256 blocks
  int inode, jnode;
  if (isi64) {
    const long long* p = (const long long*)eidx;
    inode = (int)p[e]; jnode = (int)p[E_EDGES + e];
  } else {
    const int* p = (const int*)eidx;
    inode = p[e]; jnode = p[E_EDGES + e];
  }

  const short8* ar = (const short8*)(Atb + (size_t)inode * 32);
  const short8* br = (const short8*)(Btb + (size_t)jnode * 32);
  short8 a0 = ar[0], a1 = ar[1], a2 = ar[2], a3 = ar[3];
  short8 b0 = br[0], b1 = br[1], b2 = br[2], b3 = br[3];

  float p0[16], p1[16];
#pragma unroll
  for (int j = 0; j < 8; ++j) {
    p0[j]     = bf2f((u16)a0[j]) * bf2f((u16)b0[j]);
    p0[8 + j] = bf2f((u16)a1[j]) * bf2f((u16)b1[j]);
    p1[j]     = bf2f((u16)a2[j]) * bf2f((u16)b2[j]);
    p1[8 + j] = bf2f((u16)a3[j]) * bf2f((u16)b3[j]);
  }

#pragma unroll
  for (int l = 0; l < L_DIM; ++l) {
    float s0 = 0.f, s1 = 0.f;
#pragma unroll
    for (int r = 0; r < R_DIM; ++r) {
      float g = gf[l * R_DIM + r];
      s0 += g * p0[r];
      s1 += g * p1[r];
    }
    size_t i0 = (size_t)l * E_EDGES + e;
    size_t i1 = (size_t)(L_DIM + l) * E_EDGES + e;
    if (isf32) {
      ((float*)out)[i0] = s0; ((float*)out)[i1] = s1;
    } else {
      ((u16*)out)[i0] = f2bf(s0); ((u16*)out)[i1] = f2bf(s1);
    }
  }
}

extern "C" void kernel_launch(void* const* d_in, const int* in_sizes, int n_in,
                              void* d_out, int out_size, void* d_ws, size_t ws_size,
                              hipStream_t stream) {
  const void* X     = d_in[0];
  const void* eidx  = d_in[1];
  const void* W1s   = d_in[2];
  const void* b1s   = d_in[3];
  const void* W2s   = d_in[4];
  const void* b2s   = d_in[5];
  const void* W1d   = d_in[6];
  const void* b1d   = d_in[7];
  const void* W2d   = d_in[8];
  const void* b2d   = d_in[9];
  const void* gamma = d_in[10];

  u16* Atb   = (u16*)d_ws;
  u16* Btb   = Atb + TAB_U16;
  int* flags = (int*)(Btb + TAB_U16);

  hipLaunchKernelGGL(detect_kernel, dim3(1), dim3(256), 0, stream,
                     (const u16*)W1s, (const u32*)eidx, flags);
  hipLaunchKernelGGL(mlp_kernel, dim3(512), dim3(256), 0, stream,
                     X, W1s, b1s, W2s, b2s, W1d, b1d, W2d, b2d, Atb, Btb, flags);
  hipLaunchKernelGGL(edge_kernel, dim3(E_EDGES / 256), dim3(256), 0, stream,
                     eidx, Atb, Btb, gamma, d_out, flags);
}